// Round 9
// baseline (5813.594 us; speedup 1.0000x reference)
//
#include <hip/hip_runtime.h>

// LSTM_63402307223694 — Round 9: weight-read-once step grid.
// B=64, T=256, D_IN=256, H=1024, D_OUT=1, 3 layers, gates i,f,g,o.
//
// Change vs R7/R8: step grid (128 nblk, 3 l) with mp eliminated — each block
// covers ALL 64 batches (4 mt) x 2 nsub (8 j-cols), so every weight byte is
// fetched from L3 exactly once per dispatch (was 2x: mp-pair on different
// XCDs both missed L2). Weight L3 stream: 160 -> 80 MB/dispatch.
// Wave = 4 mt x 2 nsub = 8 accs; K-split 8 (l=0) / 4+4 rec|in (l>0).
// Non-atomic LDS slot reduction (gbuf[8][64][32] = 64 KB), fused pointwise +
// A-frag repack. No register ping-pong (R8 proved it neutral).

#define BB 64
#define TT 256
#define DIN 256
#define HH 1024
#define G4 4096
#define TCHUNK 64
#define HFRAG (BB * HH)  // shorts per frag buffer (128 KB)

typedef __attribute__((ext_vector_type(8))) short short8;
typedef __attribute__((ext_vector_type(4))) float floatx4;

__device__ __forceinline__ unsigned short bf16_rne(float f) {
  union { float f; unsigned int u; } v; v.f = f;
  unsigned int lsb = (v.u >> 16) & 1u;
  v.u += 0x7fffu + lsb;
  return (unsigned short)(v.u >> 16);
}
__device__ __forceinline__ float bf16_to_f(unsigned short b) {
  union { float f; unsigned int u; } v; v.u = ((unsigned int)b) << 16;
  return v.f;
}

__global__ __launch_bounds__(256) void bias_add(
    const float* __restrict__ a, const float* __restrict__ b,
    float* __restrict__ o) {
  int i = blockIdx.x * 256 + threadIdx.x;
  o[i] = a[i] + b[i];
}

// ---- pack a [4096 x 1024] weight -> gate-interleaved B-frags (NKK=32) ----
__global__ __launch_bounds__(256) void pack_w(
    const float* __restrict__ w, unsigned short* __restrict__ bhi,
    unsigned short* __restrict__ blo) {
  int idx = blockIdx.x * 256 + threadIdx.x;  // 524288 total
  int lane = idx & 63;
  int kk = (idx >> 6) & 31;
  int nsub = idx >> 11;
  int n = lane & 15, q = lane >> 4;
  int jj = n >> 2, g = n & 3;
  int row = g * HH + nsub * 4 + jj;
  int kbase = kk * 32 + q * 8;
  const float* src = w + (size_t)row * HH + kbase;
  unsigned short h8[8], l8[8];
#pragma unroll
  for (int e = 0; e < 8; ++e) {
    float f = src[e];
    unsigned short hb = bf16_rne(f);
    h8[e] = hb;
    l8[e] = bf16_rne(f - bf16_to_f(hb));
  }
  *(short8*)(bhi + (size_t)idx * 8) = *(short8*)h8;
  *(short8*)(blo + (size_t)idx * 8) = *(short8*)l8;
}

// ---- pack w_ih[0] -> proj B-frags (direct n rows), K=256 (NKK=8) ----
__global__ __launch_bounds__(256) void pack_wih0(
    const float* __restrict__ w, unsigned short* __restrict__ bh,
    unsigned short* __restrict__ bl) {
  int idx = blockIdx.x * 256 + threadIdx.x;  // 131072
  int lane = idx & 63;
  int kk = (idx >> 6) & 7;
  int nsub = idx >> 9;
  int n = nsub * 16 + (lane & 15);
  int kbase = kk * 32 + (lane >> 4) * 8;
  const float* src = w + (size_t)n * DIN + kbase;
  unsigned short h8[8], l8[8];
#pragma unroll
  for (int e = 0; e < 8; ++e) {
    float f = src[e];
    unsigned short hb = bf16_rne(f);
    h8[e] = hb;
    l8[e] = bf16_rne(f - bf16_to_f(hb));
  }
  *(short8*)(bh + (size_t)idx * 8) = *(short8*)h8;
  *(short8*)(bl + (size_t)idx * 8) = *(short8*)l8;
}

// ---- pack x -> layer-0 proj A-frags. Row R = t*64+b, K=256 (NKK=8) ----
__global__ __launch_bounds__(256) void pack_x(
    const float* __restrict__ x, unsigned short* __restrict__ ph,
    unsigned short* __restrict__ pl) {
  int idx = blockIdx.x * 256 + threadIdx.x;  // 524288
  int lane = idx & 63;
  int kk = (idx >> 6) & 7;
  int mt = idx >> 9;
  int m2 = lane & 15, q = lane >> 4;
  int R = mt * 16 + m2;
  int t = R >> 6, b = R & 63;
  int k = kk * 32 + q * 8;
  const float* src = x + (size_t)b * (DIN * TT) + (size_t)t * DIN + k;
  unsigned short h8[8], l8[8];
#pragma unroll
  for (int e = 0; e < 8; ++e) {
    float f = src[e];
    unsigned short hb = bf16_rne(f);
    h8[e] = hb;
    l8[e] = bf16_rne(f - bf16_to_f(hb));
  }
  *(short8*)(ph + (size_t)idx * 8) = *(short8*)h8;
  *(short8*)(pl + (size_t)idx * 8) = *(short8*)l8;
}

// ---- layer-0 projection GEMM (chunk of 64 t): M=4096, N=4096, K=256 ----
__global__ __launch_bounds__(256) void proj_mfma(
    const unsigned short* __restrict__ PAh,
    const unsigned short* __restrict__ PAl,
    const unsigned short* __restrict__ PBh,
    const unsigned short* __restrict__ PBl,
    const float* __restrict__ bias, float* __restrict__ xg, int NKK) {
  const int tid = threadIdx.x, lane = tid & 63, w = tid >> 6;
  const int mw = w & 1, nw = w >> 1;
  const int mtB = blockIdx.y * 8 + mw * 4;
  const int nsB = blockIdx.x * 8 + nw * 4;
  const short8* A8h = (const short8*)PAh;
  const short8* A8l = (const short8*)PAl;
  const short8* B8h = (const short8*)PBh;
  const short8* B8l = (const short8*)PBl;
  floatx4 acc[4][4] = {};
  for (int kk = 0; kk < NKK; ++kk) {
    short8 ah[4], al[4], bh[4], bl[4];
#pragma unroll
    for (int i = 0; i < 4; ++i) {
      size_t s = ((size_t)(mtB + i) * NKK + kk) * 64 + lane;
      ah[i] = A8h[s];
      al[i] = A8l[s];
    }
#pragma unroll
    for (int j = 0; j < 4; ++j) {
      size_t s = ((size_t)(nsB + j) * NKK + kk) * 64 + lane;
      bh[j] = B8h[s];
      bl[j] = B8l[s];
    }
#pragma unroll
    for (int i = 0; i < 4; ++i)
#pragma unroll
      for (int j = 0; j < 4; ++j) {
        acc[i][j] = __builtin_amdgcn_mfma_f32_16x16x32_bf16(ah[i], bh[j], acc[i][j], 0, 0, 0);
        acc[i][j] = __builtin_amdgcn_mfma_f32_16x16x32_bf16(ah[i], bl[j], acc[i][j], 0, 0, 0);
        acc[i][j] = __builtin_amdgcn_mfma_f32_16x16x32_bf16(al[i], bh[j], acc[i][j], 0, 0, 0);
      }
  }
  const int col = lane & 15, rowq = lane >> 4;
#pragma unroll
  for (int j = 0; j < 4; ++j) {
    int n = (nsB + j) * 16 + col;
    float bz = bias[n];
#pragma unroll
    for (int i = 0; i < 4; ++i) {
      int mbase = (mtB + i) * 16 + rowq * 4;
#pragma unroll
      for (int r = 0; r < 4; ++r)
        xg[(size_t)(mbase + r) * G4 + n] = acc[i][j][r] + bz;
    }
  }
}

// ---- diagonal LSTM step v5: weight-read-once ----
// grid (128 nblk, 3 l), 512 thr = 8 waves. Block: 64 b x 2 nsub (8 j-cols).
// H frag layout: frag(l, parity, hi/lo) = H + ((l*2+p)*2+w)*HFRAG.
__global__ __launch_bounds__(512, 3) void lstm_step_diag5(
    unsigned short* __restrict__ H,
    const unsigned short* __restrict__ Whh_h0, const unsigned short* __restrict__ Whh_l0,
    const unsigned short* __restrict__ Whh_h1, const unsigned short* __restrict__ Whh_l1,
    const unsigned short* __restrict__ Whh_h2, const unsigned short* __restrict__ Whh_l2,
    const unsigned short* __restrict__ Wih_h1, const unsigned short* __restrict__ Wih_l1,
    const unsigned short* __restrict__ Wih_h2, const unsigned short* __restrict__ Wih_l2,
    const float* __restrict__ xg,     // layer-0 chunk [64, B, 4H]
    const float* __restrict__ bias,   // [3][4096]
    float* __restrict__ c_all,        // [3][B*H]
    float* __restrict__ hlast,        // [B*H]
    int d) {
  const int l = blockIdx.y;
  const int t = d - l;
  if (t < 0 || t >= TT) return;
  __shared__ float gbuf[8][64][32];  // 64 KB, per-wave slots
  const int tid = threadIdx.x, lane = tid & 63, w = tid >> 6;
  const int nblk = blockIdx.x;   // 2 nsub = 8 j
  const int ns0 = nblk * 2;

  const size_t rec_off = ((size_t)(l * 2 + ((t + 1) & 1)) * 2) * HFRAG;
  const short8 *pah, *pal, *pbh, *pbl;
  int kkB, kkE;
  if (l == 0) {
    pah = (const short8*)(H + rec_off);
    pal = (const short8*)(H + rec_off + HFRAG);
    pbh = (const short8*)Whh_h0;
    pbl = (const short8*)Whh_l0;
    kkB = w * 4;
    kkE = kkB + 4;
  } else {
    if (w < 4) {  // recurrence GEMM, K-quarter w
      pah = (const short8*)(H + rec_off);
      pal = (const short8*)(H + rec_off + HFRAG);
      pbh = (const short8*)((l == 1) ? Whh_h1 : Whh_h2);
      pbl = (const short8*)((l == 1) ? Whh_l1 : Whh_l2);
      kkB = w * 8;
    } else {  // input GEMM, K-quarter w-4
      const size_t in_off = ((size_t)((l - 1) * 2 + (t & 1)) * 2) * HFRAG;
      pah = (const short8*)(H + in_off);
      pal = (const short8*)(H + in_off + HFRAG);
      pbh = (const short8*)((l == 1) ? Wih_h1 : Wih_h2);
      pbl = (const short8*)((l == 1) ? Wih_l1 : Wih_l2);
      kkB = (w - 4) * 8;
    }
    kkE = kkB + 8;
  }

  floatx4 acc[4][2] = {};  // [mt][nsub]
  for (int kk = kkB; kk < kkE; ++kk) {
    short8 ah[4], al[4], bh[2], bl[2];
#pragma unroll
    for (int i = 0; i < 4; ++i) {
      size_t sa = ((size_t)i * 32 + kk) * 64 + lane;
      ah[i] = pah[sa];
      al[i] = pal[sa];
    }
#pragma unroll
    for (int j = 0; j < 2; ++j) {
      size_t sb = ((size_t)(ns0 + j) * 32 + kk) * 64 + lane;
      bh[j] = pbh[sb];
      bl[j] = pbl[sb];
    }
#pragma unroll
    for (int i = 0; i < 4; ++i)
#pragma unroll
      for (int j = 0; j < 2; ++j) {
        acc[i][j] = __builtin_amdgcn_mfma_f32_16x16x32_bf16(ah[i], bh[j], acc[i][j], 0, 0, 0);
        acc[i][j] = __builtin_amdgcn_mfma_f32_16x16x32_bf16(ah[i], bl[j], acc[i][j], 0, 0, 0);
        acc[i][j] = __builtin_amdgcn_mfma_f32_16x16x32_bf16(al[i], bh[j], acc[i][j], 0, 0, 0);
      }
  }
  // write partials to this wave's slot (disjoint, no atomics)
  {
    const int col = lane & 15, rowq = lane >> 4;
#pragma unroll
    for (int i = 0; i < 4; ++i)
#pragma unroll
      for (int j = 0; j < 2; ++j)
#pragma unroll
        for (int r = 0; r < 4; ++r)
          gbuf[w][i * 16 + rowq * 4 + r][j * 16 + col] = acc[i][j][r];
  }
  __syncthreads();
  // epilogue: 512 outputs = 64 b x 8 j, one per thread
  {
    const int bl = tid >> 3;   // 0..63
    const int jl = tid & 7;    // 0..7
    const int nl0 = (jl >> 2) * 16 + (jl & 3) * 4;
    float4 s = *(float4*)&gbuf[0][bl][nl0];
#pragma unroll
    for (int ww = 1; ww < 8; ++ww) {
      float4 p = *(float4*)&gbuf[ww][bl][nl0];
      s.x += p.x; s.y += p.y; s.z += p.z; s.w += p.w;
    }
    const int b = bl;
    const int j = nblk * 8 + jl;
    float gi, gf, gg, go;
    if (l == 0) {
      int tl = t & (TCHUNK - 1);
      const float* xgp = xg + (size_t)(tl * BB + b) * G4 + j;
      gi = s.x + xgp[0];
      gf = s.y + xgp[HH];
      gg = s.z + xgp[2 * HH];
      go = s.w + xgp[3 * HH];
    } else {
      const float* bz = bias + (size_t)l * G4;
      gi = s.x + bz[j];
      gf = s.y + bz[HH + j];
      gg = s.z + bz[2 * HH + j];
      go = s.w + bz[3 * HH + j];
    }
    size_t hidx = (size_t)b * HH + j;
    float* c_cur = c_all + (size_t)l * (BB * HH);
    float cprev = c_cur[hidx];
    float ig = 1.f / (1.f + __expf(-gi));
    float fg = 1.f / (1.f + __expf(-gf));
    float g2 = tanhf(gg);
    float og = 1.f / (1.f + __expf(-go));
    float cn = fg * cprev + ig * g2;
    float hn = og * tanhf(cn);
    c_cur[hidx] = cn;
    unsigned short hb = bf16_rne(hn);
    unsigned short lb = bf16_rne(hn - bf16_to_f(hb));
    size_t slotN = (((size_t)(b >> 4) * 32 + (j >> 5)) * 64 +
                    ((j >> 3) & 3) * 16 + (b & 15)) * 8 + (j & 7);
    unsigned short* Nh = H + ((size_t)(l * 2 + (t & 1)) * 2) * HFRAG;
    Nh[slotN] = hb;
    Nh[HFRAG + slotN] = lb;
    if (l == 2 && t == TT - 1) hlast[hidx] = hn;
  }
}

// ---- final FC: out[b] = hlast[b,:] . fc_w + fc_b ----
__global__ __launch_bounds__(256) void final_fc(
    const float* __restrict__ hlast, const float* __restrict__ fc_w,
    const float* __restrict__ fc_b, float* __restrict__ out) {
  int b = blockIdx.x;
  const float* hrow = hlast + (size_t)b * HH;
  float s = 0.f;
  for (int j = threadIdx.x; j < HH; j += 256) s += hrow[j] * fc_w[j];
#pragma unroll
  for (int off = 32; off > 0; off >>= 1) s += __shfl_down(s, off, 64);
  __shared__ float wsum[4];
  int wv = threadIdx.x >> 6, ln = threadIdx.x & 63;
  if (ln == 0) wsum[wv] = s;
  __syncthreads();
  if (threadIdx.x == 0) out[b] = wsum[0] + wsum[1] + wsum[2] + wsum[3] + fc_b[0];
}

extern "C" void kernel_launch(void* const* d_in, const int* in_sizes, int n_in,
                              void* d_out, int out_size, void* d_ws,
                              size_t ws_size, hipStream_t stream) {
  const float* x = (const float*)d_in[0];
  const float* w_ih[3] = {(const float*)d_in[1], (const float*)d_in[5],
                          (const float*)d_in[9]};
  const float* w_hh[3] = {(const float*)d_in[2], (const float*)d_in[6],
                          (const float*)d_in[10]};
  const float* b_ih[3] = {(const float*)d_in[3], (const float*)d_in[7],
                          (const float*)d_in[11]};
  const float* b_hh[3] = {(const float*)d_in[4], (const float*)d_in[8],
                          (const float*)d_in[12]};
  const float* fc_w = (const float*)d_in[13];
  const float* fc_b = (const float*)d_in[14];
  float* out = (float*)d_out;

  char* ws = (char*)d_ws;
  size_t off = 0;
  auto alloc = [&](size_t bytes) {
    void* p = (void*)(ws + off);
    off += (bytes + 255) & ~(size_t)255;
    return p;
  };
  unsigned short *Whh_h[3], *Whh_l[3];
  for (int l = 0; l < 3; ++l) {
    Whh_h[l] = (unsigned short*)alloc((size_t)G4 * HH * 2);
    Whh_l[l] = (unsigned short*)alloc((size_t)G4 * HH * 2);
  }
  unsigned short *Wih_h[3], *Wih_l[3];
  for (int l = 1; l < 3; ++l) {
    Wih_h[l] = (unsigned short*)alloc((size_t)G4 * HH * 2);
    Wih_l[l] = (unsigned short*)alloc((size_t)G4 * HH * 2);
  }
  unsigned short* PB0h = (unsigned short*)alloc((size_t)G4 * DIN * 2);
  unsigned short* PB0l = (unsigned short*)alloc((size_t)G4 * DIN * 2);
  float* bias_all = (float*)alloc((size_t)3 * G4 * 4);
  unsigned short* PAxh = (unsigned short*)alloc((size_t)TT * BB * DIN * 2);
  unsigned short* PAxl = (unsigned short*)alloc((size_t)TT * BB * DIN * 2);
  unsigned short* Hfr = (unsigned short*)alloc((size_t)3 * 2 * 2 * HFRAG * 2);
  float* c_all = (float*)alloc((size_t)3 * BB * HH * 4);
  float* hlast = (float*)alloc((size_t)BB * HH * 4);
  float* xg = (float*)alloc((size_t)TCHUNK * BB * G4 * 4);
  // total ~150 MB

  for (int l = 0; l < 3; ++l) {
    pack_w<<<2048, 256, 0, stream>>>(w_hh[l], Whh_h[l], Whh_l[l]);
    bias_add<<<16, 256, 0, stream>>>(b_ih[l], b_hh[l], bias_all + (size_t)l * G4);
  }
  pack_w<<<2048, 256, 0, stream>>>(w_ih[1], Wih_h[1], Wih_l[1]);
  pack_w<<<2048, 256, 0, stream>>>(w_ih[2], Wih_h[2], Wih_l[2]);
  pack_wih0<<<512, 256, 0, stream>>>(w_ih[0], PB0h, PB0l);
  pack_x<<<2048, 256, 0, stream>>>(x, PAxh, PAxl);

  for (int l = 0; l < 3; ++l)
    hipMemsetAsync(Hfr + ((size_t)(l * 2 + 1) * 2) * HFRAG, 0,
                   (size_t)2 * HFRAG * 2, stream);
  hipMemsetAsync(c_all, 0, (size_t)3 * BB * HH * 4, stream);

  for (int d = 0; d < TT + 2; ++d) {
    if ((d & (TCHUNK - 1)) == 0 && d < TT) {
      int c = d / TCHUNK;
      size_t aoff = (size_t)c * 256 * 8 * 512;
      proj_mfma<<<dim3(32, 32), 256, 0, stream>>>(
          PAxh + aoff, PAxl + aoff, PB0h, PB0l, bias_all, xg, 8);
    }
    lstm_step_diag5<<<dim3(128, 3), 512, 0, stream>>>(
        Hfr, Whh_h[0], Whh_l[0], Whh_h[1], Whh_l[1], Whh_h[2], Whh_l[2],
        Wih_h[1], Wih_l[1], Wih_h[2], Wih_l[2], xg, bias_all, c_all, hlast, d);
  }
  final_fc<<<BB, 256, 0, stream>>>(hlast, fc_w, fc_b, out);
}

// Round 10
// 4180.015 us; speedup vs baseline: 1.3908x; 1.3908x over previous
//
#include <hip/hip_runtime.h>

// LSTM_63402307223694 — Round 10: R7 structure + 2-pass split (drop W-lo).
// B=64, T=256, D_IN=256, H=1024, D_OUT=1, 3 layers, gates i,f,g,o.
//
// vs R7 (5.46 ms, best): step kernel uses W in bf16-hi ONLY (drops the
// Ah*Bl MFMA pass): per kk 8 loads -> 16 MFMAs; issued operand bytes
// 240 -> 160 MB/dispatch, MFMA -33%. A (h) stays split hi+lo, layer-0
// proj stays exact 3-pass. Expected absmax ~1e-4 (W bf16 rounding only,
// threshold 6.7e-4). Grid/reduction/epilogue identical to R7.

#define BB 64
#define TT 256
#define DIN 256
#define HH 1024
#define G4 4096
#define TCHUNK 64
#define HFRAG (BB * HH)  // shorts per frag buffer (128 KB)

typedef __attribute__((ext_vector_type(8))) short short8;
typedef __attribute__((ext_vector_type(4))) float floatx4;

__device__ __forceinline__ unsigned short bf16_rne(float f) {
  union { float f; unsigned int u; } v; v.f = f;
  unsigned int lsb = (v.u >> 16) & 1u;
  v.u += 0x7fffu + lsb;
  return (unsigned short)(v.u >> 16);
}
__device__ __forceinline__ float bf16_to_f(unsigned short b) {
  union { float f; unsigned int u; } v; v.u = ((unsigned int)b) << 16;
  return v.f;
}

__global__ __launch_bounds__(256) void bias_add(
    const float* __restrict__ a, const float* __restrict__ b,
    float* __restrict__ o) {
  int i = blockIdx.x * 256 + threadIdx.x;
  o[i] = a[i] + b[i];
}

// ---- pack a [4096 x 1024] weight -> gate-interleaved B-frags (NKK=32) ----
__global__ __launch_bounds__(256) void pack_w(
    const float* __restrict__ w, unsigned short* __restrict__ bhi,
    unsigned short* __restrict__ blo) {
  int idx = blockIdx.x * 256 + threadIdx.x;  // 524288 total
  int lane = idx & 63;
  int kk = (idx >> 6) & 31;
  int nsub = idx >> 11;
  int n = lane & 15, q = lane >> 4;
  int jj = n >> 2, g = n & 3;
  int row = g * HH + nsub * 4 + jj;
  int kbase = kk * 32 + q * 8;
  const float* src = w + (size_t)row * HH + kbase;
  unsigned short h8[8], l8[8];
#pragma unroll
  for (int e = 0; e < 8; ++e) {
    float f = src[e];
    unsigned short hb = bf16_rne(f);
    h8[e] = hb;
    l8[e] = bf16_rne(f - bf16_to_f(hb));
  }
  *(short8*)(bhi + (size_t)idx * 8) = *(short8*)h8;
  if (blo) *(short8*)(blo + (size_t)idx * 8) = *(short8*)l8;
}

// ---- pack w_ih[0] -> proj B-frags (direct n rows), K=256 (NKK=8) ----
__global__ __launch_bounds__(256) void pack_wih0(
    const float* __restrict__ w, unsigned short* __restrict__ bh,
    unsigned short* __restrict__ bl) {
  int idx = blockIdx.x * 256 + threadIdx.x;  // 131072
  int lane = idx & 63;
  int kk = (idx >> 6) & 7;
  int nsub = idx >> 9;
  int n = nsub * 16 + (lane & 15);
  int kbase = kk * 32 + (lane >> 4) * 8;
  const float* src = w + (size_t)n * DIN + kbase;
  unsigned short h8[8], l8[8];
#pragma unroll
  for (int e = 0; e < 8; ++e) {
    float f = src[e];
    unsigned short hb = bf16_rne(f);
    h8[e] = hb;
    l8[e] = bf16_rne(f - bf16_to_f(hb));
  }
  *(short8*)(bh + (size_t)idx * 8) = *(short8*)h8;
  *(short8*)(bl + (size_t)idx * 8) = *(short8*)l8;
}

// ---- pack x -> layer-0 proj A-frags. Row R = t*64+b, K=256 (NKK=8) ----
__global__ __launch_bounds__(256) void pack_x(
    const float* __restrict__ x, unsigned short* __restrict__ ph,
    unsigned short* __restrict__ pl) {
  int idx = blockIdx.x * 256 + threadIdx.x;  // 524288
  int lane = idx & 63;
  int kk = (idx >> 6) & 7;
  int mt = idx >> 9;
  int m2 = lane & 15, q = lane >> 4;
  int R = mt * 16 + m2;
  int t = R >> 6, b = R & 63;
  int k = kk * 32 + q * 8;
  const float* src = x + (size_t)b * (DIN * TT) + (size_t)t * DIN + k;
  unsigned short h8[8], l8[8];
#pragma unroll
  for (int e = 0; e < 8; ++e) {
    float f = src[e];
    unsigned short hb = bf16_rne(f);
    h8[e] = hb;
    l8[e] = bf16_rne(f - bf16_to_f(hb));
  }
  *(short8*)(ph + (size_t)idx * 8) = *(short8*)h8;
  *(short8*)(pl + (size_t)idx * 8) = *(short8*)l8;
}

// ---- layer-0 projection GEMM (chunk of 64 t): M=4096, N=4096, K=256 ----
__global__ __launch_bounds__(256) void proj_mfma(
    const unsigned short* __restrict__ PAh,
    const unsigned short* __restrict__ PAl,
    const unsigned short* __restrict__ PBh,
    const unsigned short* __restrict__ PBl,
    const float* __restrict__ bias, float* __restrict__ xg, int NKK) {
  const int tid = threadIdx.x, lane = tid & 63, w = tid >> 6;
  const int mw = w & 1, nw = w >> 1;
  const int mtB = blockIdx.y * 8 + mw * 4;
  const int nsB = blockIdx.x * 8 + nw * 4;
  const short8* A8h = (const short8*)PAh;
  const short8* A8l = (const short8*)PAl;
  const short8* B8h = (const short8*)PBh;
  const short8* B8l = (const short8*)PBl;
  floatx4 acc[4][4] = {};
  for (int kk = 0; kk < NKK; ++kk) {
    short8 ah[4], al[4], bh[4], bl[4];
#pragma unroll
    for (int i = 0; i < 4; ++i) {
      size_t s = ((size_t)(mtB + i) * NKK + kk) * 64 + lane;
      ah[i] = A8h[s];
      al[i] = A8l[s];
    }
#pragma unroll
    for (int j = 0; j < 4; ++j) {
      size_t s = ((size_t)(nsB + j) * NKK + kk) * 64 + lane;
      bh[j] = B8h[s];
      bl[j] = B8l[s];
    }
#pragma unroll
    for (int i = 0; i < 4; ++i)
#pragma unroll
      for (int j = 0; j < 4; ++j) {
        acc[i][j] = __builtin_amdgcn_mfma_f32_16x16x32_bf16(ah[i], bh[j], acc[i][j], 0, 0, 0);
        acc[i][j] = __builtin_amdgcn_mfma_f32_16x16x32_bf16(ah[i], bl[j], acc[i][j], 0, 0, 0);
        acc[i][j] = __builtin_amdgcn_mfma_f32_16x16x32_bf16(al[i], bh[j], acc[i][j], 0, 0, 0);
      }
  }
  const int col = lane & 15, rowq = lane >> 4;
#pragma unroll
  for (int j = 0; j < 4; ++j) {
    int n = (nsB + j) * 16 + col;
    float bz = bias[n];
#pragma unroll
    for (int i = 0; i < 4; ++i) {
      int mbase = (mtB + i) * 16 + rowq * 4;
#pragma unroll
      for (int r = 0; r < 4; ++r)
        xg[(size_t)(mbase + r) * G4 + n] = acc[i][j][r] + bz;
    }
  }
}

// ---- diagonal LSTM step v6: 2-pass split (W-hi only) ----
// grid (64 nblk, 2 mp, 3 l), 512 thr = 8 waves. Identical to R7's diag3
// except the Bl loads and Ah*Bl MFMA pass are removed.
__global__ __launch_bounds__(512, 4) void lstm_step_diag6(
    unsigned short* __restrict__ H,
    const unsigned short* __restrict__ Whh_h0,
    const unsigned short* __restrict__ Whh_h1,
    const unsigned short* __restrict__ Whh_h2,
    const unsigned short* __restrict__ Wih_h1,
    const unsigned short* __restrict__ Wih_h2,
    const float* __restrict__ xg,     // layer-0 chunk [64, B, 4H]
    const float* __restrict__ bias,   // [3][4096]
    float* __restrict__ c_all,        // [3][B*H]
    float* __restrict__ hlast,        // [B*H]
    int d) {
  const int l = blockIdx.z;
  const int t = d - l;
  if (t < 0 || t >= TT) return;
  __shared__ float gbuf[8][32][64];  // 64 KB, per-wave slots
  const int tid = threadIdx.x, lane = tid & 63, w = tid >> 6;
  const int nblk = blockIdx.x;   // 4 nsub = 16 j
  const int mp = blockIdx.y;     // 2 mt = 32 batches
  const int mt0 = mp * 2;
  const int ns0 = nblk * 4;

  const size_t rec_off = ((size_t)(l * 2 + ((t + 1) & 1)) * 2) * HFRAG;
  const short8 *pah, *pal, *pbh;
  int kkB, kkE;
  if (l == 0) {
    pah = (const short8*)(H + rec_off);
    pal = (const short8*)(H + rec_off + HFRAG);
    pbh = (const short8*)Whh_h0;
    kkB = w * 4;
    kkE = kkB + 4;
  } else {
    if (w < 4) {  // recurrence GEMM, K-quarter w
      pah = (const short8*)(H + rec_off);
      pal = (const short8*)(H + rec_off + HFRAG);
      pbh = (const short8*)((l == 1) ? Whh_h1 : Whh_h2);
      kkB = w * 8;
    } else {  // input GEMM, K-quarter w-4
      const size_t in_off = ((size_t)((l - 1) * 2 + (t & 1)) * 2) * HFRAG;
      pah = (const short8*)(H + in_off);
      pal = (const short8*)(H + in_off + HFRAG);
      pbh = (const short8*)((l == 1) ? Wih_h1 : Wih_h2);
      kkB = (w - 4) * 8;
    }
    kkE = kkB + 8;
  }

  floatx4 acc[2][4] = {};  // [mt][nsub]
#pragma unroll 2
  for (int kk = kkB; kk < kkE; ++kk) {
    short8 ah[2], al[2], bh[4];
#pragma unroll
    for (int i = 0; i < 2; ++i) {
      size_t sa = ((size_t)(mt0 + i) * 32 + kk) * 64 + lane;
      ah[i] = pah[sa];
      al[i] = pal[sa];
    }
#pragma unroll
    for (int j = 0; j < 4; ++j) {
      size_t sb = ((size_t)(ns0 + j) * 32 + kk) * 64 + lane;
      bh[j] = pbh[sb];
    }
#pragma unroll
    for (int i = 0; i < 2; ++i)
#pragma unroll
      for (int j = 0; j < 4; ++j) {
        acc[i][j] = __builtin_amdgcn_mfma_f32_16x16x32_bf16(ah[i], bh[j], acc[i][j], 0, 0, 0);
        acc[i][j] = __builtin_amdgcn_mfma_f32_16x16x32_bf16(al[i], bh[j], acc[i][j], 0, 0, 0);
      }
  }
  // write partials to this wave's slot (disjoint, no atomics)
  {
    const int col = lane & 15, rowq = lane >> 4;
#pragma unroll
    for (int i = 0; i < 2; ++i)
#pragma unroll
      for (int j = 0; j < 4; ++j)
#pragma unroll
        for (int r = 0; r < 4; ++r)
          gbuf[w][i * 16 + rowq * 4 + r][j * 16 + col] = acc[i][j][r];
  }
  __syncthreads();
  // epilogue: 512 outputs = 32 b x 16 j, one per thread
  {
    const int bl = tid >> 4;   // 0..31
    const int jl = tid & 15;   // 0..15
    const int nl0 = jl * 4;
    float4 s = *(float4*)&gbuf[0][bl][nl0];
#pragma unroll
    for (int ww = 1; ww < 8; ++ww) {
      float4 p = *(float4*)&gbuf[ww][bl][nl0];
      s.x += p.x; s.y += p.y; s.z += p.z; s.w += p.w;
    }
    const int b = mp * 32 + bl;
    const int j = nblk * 16 + jl;
    float gi, gf, gg, go;
    if (l == 0) {
      int tl = t & (TCHUNK - 1);
      const float* xgp = xg + (size_t)(tl * BB + b) * G4 + j;
      gi = s.x + xgp[0];
      gf = s.y + xgp[HH];
      gg = s.z + xgp[2 * HH];
      go = s.w + xgp[3 * HH];
    } else {
      const float* bz = bias + (size_t)l * G4;
      gi = s.x + bz[j];
      gf = s.y + bz[HH + j];
      gg = s.z + bz[2 * HH + j];
      go = s.w + bz[3 * HH + j];
    }
    size_t hidx = (size_t)b * HH + j;
    float* c_cur = c_all + (size_t)l * (BB * HH);
    float cprev = c_cur[hidx];
    float ig = 1.f / (1.f + __expf(-gi));
    float fg = 1.f / (1.f + __expf(-gf));
    float g2 = tanhf(gg);
    float og = 1.f / (1.f + __expf(-go));
    float cn = fg * cprev + ig * g2;
    float hn = og * tanhf(cn);
    c_cur[hidx] = cn;
    unsigned short hb = bf16_rne(hn);
    unsigned short lb = bf16_rne(hn - bf16_to_f(hb));
    size_t slotN = (((size_t)(b >> 4) * 32 + (j >> 5)) * 64 +
                    ((j >> 3) & 3) * 16 + (b & 15)) * 8 + (j & 7);
    unsigned short* Nh = H + ((size_t)(l * 2 + (t & 1)) * 2) * HFRAG;
    Nh[slotN] = hb;
    Nh[HFRAG + slotN] = lb;
    if (l == 2 && t == TT - 1) hlast[hidx] = hn;
  }
}

// ---- final FC: out[b] = hlast[b,:] . fc_w + fc_b ----
__global__ __launch_bounds__(256) void final_fc(
    const float* __restrict__ hlast, const float* __restrict__ fc_w,
    const float* __restrict__ fc_b, float* __restrict__ out) {
  int b = blockIdx.x;
  const float* hrow = hlast + (size_t)b * HH;
  float s = 0.f;
  for (int j = threadIdx.x; j < HH; j += 256) s += hrow[j] * fc_w[j];
#pragma unroll
  for (int off = 32; off > 0; off >>= 1) s += __shfl_down(s, off, 64);
  __shared__ float wsum[4];
  int wv = threadIdx.x >> 6, ln = threadIdx.x & 63;
  if (ln == 0) wsum[wv] = s;
  __syncthreads();
  if (threadIdx.x == 0) out[b] = wsum[0] + wsum[1] + wsum[2] + wsum[3] + fc_b[0];
}

extern "C" void kernel_launch(void* const* d_in, const int* in_sizes, int n_in,
                              void* d_out, int out_size, void* d_ws,
                              size_t ws_size, hipStream_t stream) {
  const float* x = (const float*)d_in[0];
  const float* w_ih[3] = {(const float*)d_in[1], (const float*)d_in[5],
                          (const float*)d_in[9]};
  const float* w_hh[3] = {(const float*)d_in[2], (const float*)d_in[6],
                          (const float*)d_in[10]};
  const float* b_ih[3] = {(const float*)d_in[3], (const float*)d_in[7],
                          (const float*)d_in[11]};
  const float* b_hh[3] = {(const float*)d_in[4], (const float*)d_in[8],
                          (const float*)d_in[12]};
  const float* fc_w = (const float*)d_in[13];
  const float* fc_b = (const float*)d_in[14];
  float* out = (float*)d_out;

  char* ws = (char*)d_ws;
  size_t off = 0;
  auto alloc = [&](size_t bytes) {
    void* p = (void*)(ws + off);
    off += (bytes + 255) & ~(size_t)255;
    return p;
  };
  unsigned short *Whh_h[3];
  for (int l = 0; l < 3; ++l)
    Whh_h[l] = (unsigned short*)alloc((size_t)G4 * HH * 2);
  unsigned short *Wih_h[3];
  for (int l = 1; l < 3; ++l)
    Wih_h[l] = (unsigned short*)alloc((size_t)G4 * HH * 2);
  unsigned short* PB0h = (unsigned short*)alloc((size_t)G4 * DIN * 2);
  unsigned short* PB0l = (unsigned short*)alloc((size_t)G4 * DIN * 2);
  float* bias_all = (float*)alloc((size_t)3 * G4 * 4);
  unsigned short* PAxh = (unsigned short*)alloc((size_t)TT * BB * DIN * 2);
  unsigned short* PAxl = (unsigned short*)alloc((size_t)TT * BB * DIN * 2);
  unsigned short* Hfr = (unsigned short*)alloc((size_t)3 * 2 * 2 * HFRAG * 2);
  float* c_all = (float*)alloc((size_t)3 * BB * HH * 4);
  float* hlast = (float*)alloc((size_t)BB * HH * 4);
  float* xg = (float*)alloc((size_t)TCHUNK * BB * G4 * 4);
  // total ~110 MB

  for (int l = 0; l < 3; ++l) {
    pack_w<<<2048, 256, 0, stream>>>(w_hh[l], Whh_h[l], nullptr);
    bias_add<<<16, 256, 0, stream>>>(b_ih[l], b_hh[l], bias_all + (size_t)l * G4);
  }
  pack_w<<<2048, 256, 0, stream>>>(w_ih[1], Wih_h[1], nullptr);
  pack_w<<<2048, 256, 0, stream>>>(w_ih[2], Wih_h[2], nullptr);
  pack_wih0<<<512, 256, 0, stream>>>(w_ih[0], PB0h, PB0l);
  pack_x<<<2048, 256, 0, stream>>>(x, PAxh, PAxl);

  for (int l = 0; l < 3; ++l)
    hipMemsetAsync(Hfr + ((size_t)(l * 2 + 1) * 2) * HFRAG, 0,
                   (size_t)2 * HFRAG * 2, stream);
  hipMemsetAsync(c_all, 0, (size_t)3 * BB * HH * 4, stream);

  for (int d = 0; d < TT + 2; ++d) {
    if ((d & (TCHUNK - 1)) == 0 && d < TT) {
      int c = d / TCHUNK;
      size_t aoff = (size_t)c * 256 * 8 * 512;
      proj_mfma<<<dim3(32, 32), 256, 0, stream>>>(
          PAxh + aoff, PAxl + aoff, PB0h, PB0l, bias_all, xg, 8);
    }
    lstm_step_diag6<<<dim3(64, 2, 3), 512, 0, stream>>>(
        Hfr, Whh_h[0], Whh_h[1], Whh_h[2], Wih_h[1], Wih_h[2],
        xg, bias_all, c_all, hlast, d);
  }
  final_fc<<<BB, 256, 0, stream>>>(hlast, fc_w, fc_b, out);
}

// Round 11
// 3409.176 us; speedup vs baseline: 1.7053x; 1.2261x over previous
//
#include <hip/hip_runtime.h>

// LSTM_63402307223694 — Round 11: R10 + single-bf16 h (drop A-lo pass).
// B=64, T=256, D_IN=256, H=1024, D_OUT=1, 3 layers, gates i,f,g,o.
//
// vs R10 (4.18 ms): recurrence/inter-layer h stored as ONE bf16 frag
// (no lo). Per kk: 6 loads -> 8 MFMAs; issued operand bytes 160 -> 120
// MB/dispatch. Expected absmax ~2e-4 (W + h bf16 rounding, threshold
// 6.7e-4). Layer-0 x-projection stays exact 3-pass split-bf16.
// Empirical model: t_step = 2.8us + issued_MB/16TB/s -> ~10.3 us/step.

#define BB 64
#define TT 256
#define DIN 256
#define HH 1024
#define G4 4096
#define TCHUNK 64
#define HFRAG (BB * HH)  // shorts per frag buffer (128 KB)

typedef __attribute__((ext_vector_type(8))) short short8;
typedef __attribute__((ext_vector_type(4))) float floatx4;

__device__ __forceinline__ unsigned short bf16_rne(float f) {
  union { float f; unsigned int u; } v; v.f = f;
  unsigned int lsb = (v.u >> 16) & 1u;
  v.u += 0x7fffu + lsb;
  return (unsigned short)(v.u >> 16);
}
__device__ __forceinline__ float bf16_to_f(unsigned short b) {
  union { float f; unsigned int u; } v; v.u = ((unsigned int)b) << 16;
  return v.f;
}

__global__ __launch_bounds__(256) void bias_add(
    const float* __restrict__ a, const float* __restrict__ b,
    float* __restrict__ o) {
  int i = blockIdx.x * 256 + threadIdx.x;
  o[i] = a[i] + b[i];
}

// ---- pack a [4096 x 1024] weight -> gate-interleaved B-frags (NKK=32) ----
__global__ __launch_bounds__(256) void pack_w(
    const float* __restrict__ w, unsigned short* __restrict__ bhi) {
  int idx = blockIdx.x * 256 + threadIdx.x;  // 524288 total
  int lane = idx & 63;
  int kk = (idx >> 6) & 31;
  int nsub = idx >> 11;
  int n = lane & 15, q = lane >> 4;
  int jj = n >> 2, g = n & 3;
  int row = g * HH + nsub * 4 + jj;
  int kbase = kk * 32 + q * 8;
  const float* src = w + (size_t)row * HH + kbase;
  unsigned short h8[8];
#pragma unroll
  for (int e = 0; e < 8; ++e) h8[e] = bf16_rne(src[e]);
  *(short8*)(bhi + (size_t)idx * 8) = *(short8*)h8;
}

// ---- pack w_ih[0] -> proj B-frags (direct n rows), K=256 (NKK=8) ----
__global__ __launch_bounds__(256) void pack_wih0(
    const float* __restrict__ w, unsigned short* __restrict__ bh,
    unsigned short* __restrict__ bl) {
  int idx = blockIdx.x * 256 + threadIdx.x;  // 131072
  int lane = idx & 63;
  int kk = (idx >> 6) & 7;
  int nsub = idx >> 9;
  int n = nsub * 16 + (lane & 15);
  int kbase = kk * 32 + (lane >> 4) * 8;
  const float* src = w + (size_t)n * DIN + kbase;
  unsigned short h8[8], l8[8];
#pragma unroll
  for (int e = 0; e < 8; ++e) {
    float f = src[e];
    unsigned short hb = bf16_rne(f);
    h8[e] = hb;
    l8[e] = bf16_rne(f - bf16_to_f(hb));
  }
  *(short8*)(bh + (size_t)idx * 8) = *(short8*)h8;
  *(short8*)(bl + (size_t)idx * 8) = *(short8*)l8;
}

// ---- pack x -> layer-0 proj A-frags. Row R = t*64+b, K=256 (NKK=8) ----
__global__ __launch_bounds__(256) void pack_x(
    const float* __restrict__ x, unsigned short* __restrict__ ph,
    unsigned short* __restrict__ pl) {
  int idx = blockIdx.x * 256 + threadIdx.x;  // 524288
  int lane = idx & 63;
  int kk = (idx >> 6) & 7;
  int mt = idx >> 9;
  int m2 = lane & 15, q = lane >> 4;
  int R = mt * 16 + m2;
  int t = R >> 6, b = R & 63;
  int k = kk * 32 + q * 8;
  const float* src = x + (size_t)b * (DIN * TT) + (size_t)t * DIN + k;
  unsigned short h8[8], l8[8];
#pragma unroll
  for (int e = 0; e < 8; ++e) {
    float f = src[e];
    unsigned short hb = bf16_rne(f);
    h8[e] = hb;
    l8[e] = bf16_rne(f - bf16_to_f(hb));
  }
  *(short8*)(ph + (size_t)idx * 8) = *(short8*)h8;
  *(short8*)(pl + (size_t)idx * 8) = *(short8*)l8;
}

// ---- layer-0 projection GEMM (chunk of 64 t): M=4096, N=4096, K=256 ----
__global__ __launch_bounds__(256) void proj_mfma(
    const unsigned short* __restrict__ PAh,
    const unsigned short* __restrict__ PAl,
    const unsigned short* __restrict__ PBh,
    const unsigned short* __restrict__ PBl,
    const float* __restrict__ bias, float* __restrict__ xg, int NKK) {
  const int tid = threadIdx.x, lane = tid & 63, w = tid >> 6;
  const int mw = w & 1, nw = w >> 1;
  const int mtB = blockIdx.y * 8 + mw * 4;
  const int nsB = blockIdx.x * 8 + nw * 4;
  const short8* A8h = (const short8*)PAh;
  const short8* A8l = (const short8*)PAl;
  const short8* B8h = (const short8*)PBh;
  const short8* B8l = (const short8*)PBl;
  floatx4 acc[4][4] = {};
  for (int kk = 0; kk < NKK; ++kk) {
    short8 ah[4], al[4], bh[4], bl[4];
#pragma unroll
    for (int i = 0; i < 4; ++i) {
      size_t s = ((size_t)(mtB + i) * NKK + kk) * 64 + lane;
      ah[i] = A8h[s];
      al[i] = A8l[s];
    }
#pragma unroll
    for (int j = 0; j < 4; ++j) {
      size_t s = ((size_t)(nsB + j) * NKK + kk) * 64 + lane;
      bh[j] = B8h[s];
      bl[j] = B8l[s];
    }
#pragma unroll
    for (int i = 0; i < 4; ++i)
#pragma unroll
      for (int j = 0; j < 4; ++j) {
        acc[i][j] = __builtin_amdgcn_mfma_f32_16x16x32_bf16(ah[i], bh[j], acc[i][j], 0, 0, 0);
        acc[i][j] = __builtin_amdgcn_mfma_f32_16x16x32_bf16(ah[i], bl[j], acc[i][j], 0, 0, 0);
        acc[i][j] = __builtin_amdgcn_mfma_f32_16x16x32_bf16(al[i], bh[j], acc[i][j], 0, 0, 0);
      }
  }
  const int col = lane & 15, rowq = lane >> 4;
#pragma unroll
  for (int j = 0; j < 4; ++j) {
    int n = (nsB + j) * 16 + col;
    float bz = bias[n];
#pragma unroll
    for (int i = 0; i < 4; ++i) {
      int mbase = (mtB + i) * 16 + rowq * 4;
#pragma unroll
      for (int r = 0; r < 4; ++r)
        xg[(size_t)(mbase + r) * G4 + n] = acc[i][j][r] + bz;
    }
  }
}

// ---- diagonal LSTM step v7: full-bf16 operands (W-hi x h-bf16) ----
// grid (64 nblk, 2 mp, 3 l), 512 thr = 8 waves.
// H frag layout: frag(l, parity) = H + (l*2+p)*HFRAG  (hi only).
__global__ __launch_bounds__(512, 4) void lstm_step_diag7(
    unsigned short* __restrict__ H,
    const unsigned short* __restrict__ Whh_h0,
    const unsigned short* __restrict__ Whh_h1,
    const unsigned short* __restrict__ Whh_h2,
    const unsigned short* __restrict__ Wih_h1,
    const unsigned short* __restrict__ Wih_h2,
    const float* __restrict__ xg,     // layer-0 chunk [64, B, 4H]
    const float* __restrict__ bias,   // [3][4096]
    float* __restrict__ c_all,        // [3][B*H]
    float* __restrict__ hlast,        // [B*H]
    int d) {
  const int l = blockIdx.z;
  const int t = d - l;
  if (t < 0 || t >= TT) return;
  __shared__ float gbuf[8][32][64];  // 64 KB, per-wave slots
  const int tid = threadIdx.x, lane = tid & 63, w = tid >> 6;
  const int nblk = blockIdx.x;   // 4 nsub = 16 j
  const int mp = blockIdx.y;     // 2 mt = 32 batches
  const int mt0 = mp * 2;
  const int ns0 = nblk * 4;

  const size_t rec_off = (size_t)(l * 2 + ((t + 1) & 1)) * HFRAG;
  const short8 *pah, *pbh;
  int kkB, kkE;
  if (l == 0) {
    pah = (const short8*)(H + rec_off);
    pbh = (const short8*)Whh_h0;
    kkB = w * 4;
    kkE = kkB + 4;
  } else {
    if (w < 4) {  // recurrence GEMM, K-quarter w
      pah = (const short8*)(H + rec_off);
      pbh = (const short8*)((l == 1) ? Whh_h1 : Whh_h2);
      kkB = w * 8;
    } else {  // input GEMM, K-quarter w-4
      const size_t in_off = (size_t)((l - 1) * 2 + (t & 1)) * HFRAG;
      pah = (const short8*)(H + in_off);
      pbh = (const short8*)((l == 1) ? Wih_h1 : Wih_h2);
      kkB = (w - 4) * 8;
    }
    kkE = kkB + 8;
  }

  floatx4 acc[2][4] = {};  // [mt][nsub]
#pragma unroll 2
  for (int kk = kkB; kk < kkE; ++kk) {
    short8 ah[2], bh[4];
#pragma unroll
    for (int i = 0; i < 2; ++i) {
      size_t sa = ((size_t)(mt0 + i) * 32 + kk) * 64 + lane;
      ah[i] = pah[sa];
    }
#pragma unroll
    for (int j = 0; j < 4; ++j) {
      size_t sb = ((size_t)(ns0 + j) * 32 + kk) * 64 + lane;
      bh[j] = pbh[sb];
    }
#pragma unroll
    for (int i = 0; i < 2; ++i)
#pragma unroll
      for (int j = 0; j < 4; ++j)
        acc[i][j] = __builtin_amdgcn_mfma_f32_16x16x32_bf16(ah[i], bh[j], acc[i][j], 0, 0, 0);
  }
  // write partials to this wave's slot (disjoint, no atomics)
  {
    const int col = lane & 15, rowq = lane >> 4;
#pragma unroll
    for (int i = 0; i < 2; ++i)
#pragma unroll
      for (int j = 0; j < 4; ++j)
#pragma unroll
        for (int r = 0; r < 4; ++r)
          gbuf[w][i * 16 + rowq * 4 + r][j * 16 + col] = acc[i][j][r];
  }
  __syncthreads();
  // epilogue: 512 outputs = 32 b x 16 j, one per thread
  {
    const int bl = tid >> 4;   // 0..31
    const int jl = tid & 15;   // 0..15
    const int nl0 = jl * 4;
    float4 s = *(float4*)&gbuf[0][bl][nl0];
#pragma unroll
    for (int ww = 1; ww < 8; ++ww) {
      float4 p = *(float4*)&gbuf[ww][bl][nl0];
      s.x += p.x; s.y += p.y; s.z += p.z; s.w += p.w;
    }
    const int b = mp * 32 + bl;
    const int j = nblk * 16 + jl;
    float gi, gf, gg, go;
    if (l == 0) {
      int tl = t & (TCHUNK - 1);
      const float* xgp = xg + (size_t)(tl * BB + b) * G4 + j;
      gi = s.x + xgp[0];
      gf = s.y + xgp[HH];
      gg = s.z + xgp[2 * HH];
      go = s.w + xgp[3 * HH];
    } else {
      const float* bz = bias + (size_t)l * G4;
      gi = s.x + bz[j];
      gf = s.y + bz[HH + j];
      gg = s.z + bz[2 * HH + j];
      go = s.w + bz[3 * HH + j];
    }
    size_t hidx = (size_t)b * HH + j;
    float* c_cur = c_all + (size_t)l * (BB * HH);
    float cprev = c_cur[hidx];
    float ig = 1.f / (1.f + __expf(-gi));
    float fg = 1.f / (1.f + __expf(-gf));
    float g2 = tanhf(gg);
    float og = 1.f / (1.f + __expf(-go));
    float cn = fg * cprev + ig * g2;
    float hn = og * tanhf(cn);
    c_cur[hidx] = cn;
    unsigned short hb = bf16_rne(hn);
    size_t slotN = (((size_t)(b >> 4) * 32 + (j >> 5)) * 64 +
                    ((j >> 3) & 3) * 16 + (b & 15)) * 8 + (j & 7);
    unsigned short* Nh = H + (size_t)(l * 2 + (t & 1)) * HFRAG;
    Nh[slotN] = hb;
    if (l == 2 && t == TT - 1) hlast[hidx] = hn;
  }
}

// ---- final FC: out[b] = hlast[b,:] . fc_w + fc_b ----
__global__ __launch_bounds__(256) void final_fc(
    const float* __restrict__ hlast, const float* __restrict__ fc_w,
    const float* __restrict__ fc_b, float* __restrict__ out) {
  int b = blockIdx.x;
  const float* hrow = hlast + (size_t)b * HH;
  float s = 0.f;
  for (int j = threadIdx.x; j < HH; j += 256) s += hrow[j] * fc_w[j];
#pragma unroll
  for (int off = 32; off > 0; off >>= 1) s += __shfl_down(s, off, 64);
  __shared__ float wsum[4];
  int wv = threadIdx.x >> 6, ln = threadIdx.x & 63;
  if (ln == 0) wsum[wv] = s;
  __syncthreads();
  if (threadIdx.x == 0) out[b] = wsum[0] + wsum[1] + wsum[2] + wsum[3] + fc_b[0];
}

extern "C" void kernel_launch(void* const* d_in, const int* in_sizes, int n_in,
                              void* d_out, int out_size, void* d_ws,
                              size_t ws_size, hipStream_t stream) {
  const float* x = (const float*)d_in[0];
  const float* w_ih[3] = {(const float*)d_in[1], (const float*)d_in[5],
                          (const float*)d_in[9]};
  const float* w_hh[3] = {(const float*)d_in[2], (const float*)d_in[6],
                          (const float*)d_in[10]};
  const float* b_ih[3] = {(const float*)d_in[3], (const float*)d_in[7],
                          (const float*)d_in[11]};
  const float* b_hh[3] = {(const float*)d_in[4], (const float*)d_in[8],
                          (const float*)d_in[12]};
  const float* fc_w = (const float*)d_in[13];
  const float* fc_b = (const float*)d_in[14];
  float* out = (float*)d_out;

  char* ws = (char*)d_ws;
  size_t off = 0;
  auto alloc = [&](size_t bytes) {
    void* p = (void*)(ws + off);
    off += (bytes + 255) & ~(size_t)255;
    return p;
  };
  unsigned short *Whh_h[3];
  for (int l = 0; l < 3; ++l)
    Whh_h[l] = (unsigned short*)alloc((size_t)G4 * HH * 2);
  unsigned short *Wih_h[3];
  for (int l = 1; l < 3; ++l)
    Wih_h[l] = (unsigned short*)alloc((size_t)G4 * HH * 2);
  unsigned short* PB0h = (unsigned short*)alloc((size_t)G4 * DIN * 2);
  unsigned short* PB0l = (unsigned short*)alloc((size_t)G4 * DIN * 2);
  float* bias_all = (float*)alloc((size_t)3 * G4 * 4);
  unsigned short* PAxh = (unsigned short*)alloc((size_t)TT * BB * DIN * 2);
  unsigned short* PAxl = (unsigned short*)alloc((size_t)TT * BB * DIN * 2);
  unsigned short* Hfr = (unsigned short*)alloc((size_t)3 * 2 * HFRAG * 2);
  float* c_all = (float*)alloc((size_t)3 * BB * HH * 4);
  float* hlast = (float*)alloc((size_t)BB * HH * 4);
  float* xg = (float*)alloc((size_t)TCHUNK * BB * G4 * 4);
  // total ~110 MB

  for (int l = 0; l < 3; ++l) {
    pack_w<<<2048, 256, 0, stream>>>(w_hh[l], Whh_h[l]);
    bias_add<<<16, 256, 0, stream>>>(b_ih[l], b_hh[l], bias_all + (size_t)l * G4);
  }
  pack_w<<<2048, 256, 0, stream>>>(w_ih[1], Wih_h[1]);
  pack_w<<<2048, 256, 0, stream>>>(w_ih[2], Wih_h[2]);
  pack_wih0<<<512, 256, 0, stream>>>(w_ih[0], PB0h, PB0l);
  pack_x<<<2048, 256, 0, stream>>>(x, PAxh, PAxl);

  for (int l = 0; l < 3; ++l)
    hipMemsetAsync(Hfr + (size_t)(l * 2 + 1) * HFRAG, 0,
                   (size_t)HFRAG * 2, stream);
  hipMemsetAsync(c_all, 0, (size_t)3 * BB * HH * 4, stream);

  for (int d = 0; d < TT + 2; ++d) {
    if ((d & (TCHUNK - 1)) == 0 && d < TT) {
      int c = d / TCHUNK;
      size_t aoff = (size_t)c * 256 * 8 * 512;
      proj_mfma<<<dim3(32, 32), 256, 0, stream>>>(
          PAxh + aoff, PAxl + aoff, PB0h, PB0l, bias_all, xg, 8);
    }
    lstm_step_diag7<<<dim3(64, 2, 3), 512, 0, stream>>>(
        Hfr, Whh_h[0], Whh_h[1], Whh_h[2], Wih_h[1], Wih_h[2],
        xg, bias_all, c_all, hlast, d);
  }
  final_fc<<<BB, 256, 0, stream>>>(hlast, fc_w, fc_b, out);
}